// Round 20
// baseline (174.481 us; speedup 1.0000x reference)
//
#include <hip/hip_runtime.h>
#include <hip/hip_bf16.h>

// spatial_attention: out = weights @ P1 + P2 ; P1 = H W1^T ; P2 = H W2^T + bias
//   Domain uniform (runtime-verified) -> weights fast path: w = relu(dval - dist).
//   Zero-barrier GEMMs: B staged ONCE into 128KB LDS (4 x [256][128B] XOR-swizzled
//   regions), K-loop barrier-free. R19 bug: launch_bounds(1024) let regalloc pick
//   VGPR=64 -> acc[2][8] spilled (WRITE 162MB vs 64MB true). Fix: (1024, 4) pins
//   4 waves/EU -> 128 VGPR, no spill, same 16-wave/CU occupancy the LDS allows.
//   K0  : Wbf = bf16(W); k0_check -> {dval, uniform}
//   k2a : weights -> weBuf (pre-scaled bf16), wave-per-row
//   kP  : stage W1 -> P1T[b] ; restage W2 -> P2[b] (+bias). 3 barriers total.
//   kOut: stage P1T[b] -> out = weBuf @ P1T + P2. 1 barrier.
// Workspace: Wbf 512KB @0 ; flag @512KB ; P1T 32MB @1MB ; P2 32MB @33MB ; weBuf 32MB @65MB

typedef __attribute__((ext_vector_type(4))) float  f32x4;
typedef __attribute__((ext_vector_type(8))) short  bf16x8;
typedef __attribute__((ext_vector_type(4))) short  bf16x4;

#define EPSC 1e-14f

__device__ __forceinline__ short f2bf(float v) {
  __hip_bfloat16 h = __float2bfloat16(v);
  return *reinterpret_cast<short*>(&h);
}
__device__ __forceinline__ float bf2f(unsigned short u) {
  union { unsigned int i; float f; } c; c.i = ((unsigned int)u) << 16; return c.f;
}
__device__ __forceinline__ void gload16(const void* g, void* l) {
  __builtin_amdgcn_global_load_lds(
      (const __attribute__((address_space(1))) void*)g,
      (__attribute__((address_space(3))) void*)l, 16, 0, 0);
}
__device__ __forceinline__ bf16x8 cvt8(const float* p) {
  f32x4 a = *(const f32x4*)p;
  f32x4 b = *(const f32x4*)(p + 4);
  bf16x8 r;
  r[0] = f2bf(a[0]); r[1] = f2bf(a[1]); r[2] = f2bf(a[2]); r[3] = f2bf(a[3]);
  r[4] = f2bf(b[0]); r[5] = f2bf(b[1]); r[6] = f2bf(b[2]); r[7] = f2bf(b[3]);
  return r;
}

// ---------------- K0: W fp32 -> bf16 ----------------
__global__ void k0_pack(const float* __restrict__ W, short* __restrict__ Wbf) {
  int idx = blockIdx.x * 256 + threadIdx.x;
  f32x4 v = *(const f32x4*)(W + (size_t)idx * 4);
  bf16x4 pk;
  pk[0] = f2bf(v[0]); pk[1] = f2bf(v[1]); pk[2] = f2bf(v[2]); pk[3] = f2bf(v[3]);
  *(bf16x4*)(Wbf + (size_t)idx * 4) = pk;
}

// ---------------- K0b: domain uniformity check ----------------
__global__ void k0_check(const float* __restrict__ domain, float* __restrict__ flag) {
  __shared__ int s_ok[4];
  const int t = threadIdx.x;
  float v0 = domain[0];
  bool ok = true;
  for (int x = t; x < 72 * 72; x += 256) ok = ok && (domain[x] == v0);
  unsigned long long m = __ballot(ok);
  if ((t & 63) == 0) s_ok[t >> 6] = (m == ~0ull) ? 1 : 0;
  __syncthreads();
  if (t == 0) {
    flag[0] = v0;
    flag[1] = (s_ok[0] && s_ok[1] && s_ok[2] && s_ok[3]) ? 1.f : 0.f;
  }
}

// ---------------- k2a: pre-scaled weights, wave-per-row (R9-proven) ----------------
__global__ __launch_bounds__(256) void k2a_weights(
    const float* __restrict__ dist, const float* __restrict__ bear,
    const float* __restrict__ head, const float* __restrict__ seqmask,
    const float* __restrict__ domain, const float* __restrict__ uflag,
    short* __restrict__ weBuf) {
  __shared__ float sMask[256];
  const int t = threadIdx.x;
  const int b = blockIdx.x >> 3;
  const int i0 = (blockIdx.x & 7) * 32;
  if (t < 256) sMask[t] = seqmask[b * 256 + t];
  __syncthreads();

  const int w = t >> 6, l = t & 63;
  const int j0 = l * 4;
  const float dval = uflag[0];
  const bool  uni  = uflag[1] != 0.f;
  const f32x4 mj = *(const f32x4*)(sMask + j0);

  f32x4 dv[8];
  #pragma unroll
  for (int rr = 0; rr < 8; ++rr) {
    int i = i0 + w * 8 + rr;
    dv[rr] = *(const f32x4*)(dist + ((size_t)b * 256 + i) * 256 + j0);
  }

  #pragma unroll
  for (int rr = 0; rr < 8; ++rr) {
    const int i = i0 + w * 8 + rr;
    const float mI = sMask[i];
    const size_t base = ((size_t)b * 256 + i) * 256;
    float ev[4];
    float rs = 0.f;
    if (uni) {
      #pragma unroll
      for (int e = 0; e < 4; ++e) {
        float wv = fmaxf(dval - dv[rr][e], 0.f);
        bool valid = (i != j0 + e) && (mI != 0.f) && (mj[e] != 0.f);
        float ex = (wv > 0.f) ? __expf(wv) : 0.f;
        ex = valid ? ex : 0.f;
        rs += ex;
        ev[e] = valid ? (ex + EPSC) : 0.f;
      }
    } else {
      f32x4 bv = *(const f32x4*)(bear + base + j0);
      f32x4 hv = *(const f32x4*)(head + base + j0);
      #pragma unroll
      for (int e = 0; e < 4; ++e) {
        float f1 = fminf(fmaxf(floorf((hv[e] + 2.5f) * 0.2f), 0.f), 71.f);
        float f2 = fminf(fmaxf(floorf((bv[e] + 2.5f) * 0.2f), 0.f), 71.f);
        float wv = fmaxf(domain[(int)(f1 * 72.f + f2)] - dv[rr][e], 0.f);
        bool valid = (i != j0 + e) && (mI != 0.f) && (mj[e] != 0.f);
        float ex = (wv > 0.f) ? __expf(wv) : 0.f;
        ex = valid ? ex : 0.f;
        rs += ex;
        ev[e] = valid ? (ex + EPSC) : 0.f;
      }
    }
    rs += __shfl_xor(rs, 1, 64);
    rs += __shfl_xor(rs, 2, 64);
    rs += __shfl_xor(rs, 4, 64);
    rs += __shfl_xor(rs, 8, 64);
    rs += __shfl_xor(rs, 16, 64);
    rs += __shfl_xor(rs, 32, 64);
    const float scale = 1.0f / (rs + 257.0f * EPSC);
    bf16x4 pk;
    pk[0] = f2bf(ev[0] * scale); pk[1] = f2bf(ev[1] * scale);
    pk[2] = f2bf(ev[2] * scale); pk[3] = f2bf(ev[3] * scale);
    *(bf16x4*)(weBuf + base + j0) = pk;
  }
}

// ---------------- kP: P1T[b] + P2[b], B staged once per pass ----------------
// grid 256 (block = b), block 1024 = 16 waves (wr 8 x 32 rows, wc 2 x 128 d), LDS 128K.
// (1024, 4): 4 waves/EU -> 128 VGPR cap, no spill (R19 bug fix).
__global__ __launch_bounds__(1024, 4) void kP(
    const float* __restrict__ H, const short* __restrict__ Wbf,
    const float* __restrict__ bias,
    short* __restrict__ P1T, short* __restrict__ P2) {
  extern __shared__ char sm[];                 // 4 regions x [256][128B]
  const int t = threadIdx.x;
  const int b = blockIdx.x;
  const int n0 = b * 256;
  const int wid = t >> 6, l = t & 63;
  const int lr = l & 15, lg = l >> 4;
  const int wr = wid & 7, wc = wid >> 3;
  const int r3 = l >> 3, sl = l & 7;
  const int sswz = (sl ^ r3) * 8;              // source slot pre-swizzle (shorts)
  const int sw = (lr & 7) << 4;                // read-side XOR (bytes)

  const size_t h0 = ((size_t)(n0 + wr * 32 + lr)) * 256;
  const size_t h1 = h0 + 16 * 256;

  #pragma unroll
  for (int pass = 0; pass < 2; ++pass) {
    // ---- stage W-half ONCE: 4 regions x 2 sweeps of 16KB ----
    #pragma unroll
    for (int c = 0; c < 4; ++c) {
      #pragma unroll
      for (int p = 0; p < 2; ++p) {
        int dd = wid * 8 + 128 * p + r3;
        gload16(Wbf + (size_t)dd * 512 + pass * 256 + c * 64 + sswz,
                sm + c * 32768 + (wid * 8 + 128 * p) * 128);
      }
    }
    __syncthreads();                           // only barrier of the pass

    f32x4 acc[2][8] = {};
    #pragma unroll
    for (int c = 0; c < 4; ++c) {
      #pragma unroll
      for (int sub = 0; sub < 2; ++sub) {
        const int k0 = c * 64 + sub * 32 + lg * 8;
        bf16x8 av0 = cvt8(H + h0 + k0);
        bf16x8 av1 = cvt8(H + h1 + k0);
        #pragma unroll
        for (int n = 0; n < 8; ++n) {
          const int d = wc * 128 + n * 16 + lr;
          bf16x8 bb = *(const bf16x8*)(sm + c * 32768 + d * 128 + ((sub * 64 + lg * 16) ^ sw));
          acc[0][n] = __builtin_amdgcn_mfma_f32_16x16x32_bf16(av0, bb, acc[0][n], 0, 0, 0);
          acc[1][n] = __builtin_amdgcn_mfma_f32_16x16x32_bf16(av1, bb, acc[1][n], 0, 0, 0);
        }
      }
    }

    if (pass == 0) {
      // P1T[b][d][j], transposed write
      #pragma unroll
      for (int m = 0; m < 2; ++m) {
        #pragma unroll
        for (int n = 0; n < 8; ++n) {
          const int d = wc * 128 + n * 16 + lr;
          const int j = wr * 32 + m * 16 + lg * 4;
          f32x4 v = acc[m][n];
          bf16x4 pk;
          pk[0] = f2bf(v[0]); pk[1] = f2bf(v[1]); pk[2] = f2bf(v[2]); pk[3] = f2bf(v[3]);
          *(bf16x4*)(P1T + (size_t)b * 65536 + (size_t)d * 256 + j) = pk;
        }
      }
    } else {
      // P2[b][j][d] = acc + bias
      #pragma unroll
      for (int m = 0; m < 2; ++m) {
        #pragma unroll
        for (int n = 0; n < 8; ++n) {
          const int d = wc * 128 + n * 16 + lr;
          const float bs = bias[d];
          const int row = wr * 32 + m * 16 + lg * 4;
          f32x4 v = acc[m][n];
          #pragma unroll
          for (int r = 0; r < 4; ++r)
            P2[(size_t)b * 65536 + (size_t)(row + r) * 256 + d] = f2bf(v[r] + bs);
        }
      }
    }
    __syncthreads();                           // LDS reuse boundary
  }
}

// ---------------- kOut: out = weBuf @ P1T + P2, B = P1T[b] staged once ----------------
// grid 256 (block = b), block 1024, LDS 128K, 1 barrier. (1024, 4) -> 128 VGPR.
__global__ __launch_bounds__(1024, 4) void kOut(
    const short* __restrict__ weBuf, const short* __restrict__ P1T,
    const short* __restrict__ P2, float* __restrict__ out) {
  extern __shared__ char sm[];                 // 4 regions x [256][128B]
  const int t = threadIdx.x;
  const int b = blockIdx.x;
  const int wid = t >> 6, l = t & 63;
  const int lr = l & 15, lg = l >> 4;
  const int wr = wid & 7, wc = wid >> 3;
  const int r3 = l >> 3, sl = l & 7;
  const int sswz = (sl ^ r3) * 8;
  const int sw = (lr & 7) << 4;

  const short* __restrict__ P1b = P1T + (size_t)b * 65536;
  const size_t a0 = ((size_t)b * 256 + wr * 32 + lr) * 256;
  const size_t a1 = a0 + 16 * 256;

  // ---- stage P1T[b] ONCE ----
  #pragma unroll
  for (int c = 0; c < 4; ++c) {
    #pragma unroll
    for (int p = 0; p < 2; ++p) {
      int dd = wid * 8 + 128 * p + r3;
      gload16(P1b + (size_t)dd * 256 + c * 64 + sswz,
              sm + c * 32768 + (wid * 8 + 128 * p) * 128);
    }
  }
  __syncthreads();                             // the only barrier

  f32x4 acc[2][8] = {};
  #pragma unroll
  for (int c = 0; c < 4; ++c) {
    #pragma unroll
    for (int sub = 0; sub < 2; ++sub) {
      const int k0 = c * 64 + sub * 32 + lg * 8;
      bf16x8 av0 = *(const bf16x8*)(weBuf + a0 + k0);
      bf16x8 av1 = *(const bf16x8*)(weBuf + a1 + k0);
      #pragma unroll
      for (int n = 0; n < 8; ++n) {
        const int d = wc * 128 + n * 16 + lr;
        bf16x8 bb = *(const bf16x8*)(sm + c * 32768 + d * 128 + ((sub * 64 + lg * 16) ^ sw));
        acc[0][n] = __builtin_amdgcn_mfma_f32_16x16x32_bf16(av0, bb, acc[0][n], 0, 0, 0);
        acc[1][n] = __builtin_amdgcn_mfma_f32_16x16x32_bf16(av1, bb, acc[1][n], 0, 0, 0);
      }
    }
  }

  // epilogue: + P2 (bias folded), fp32 store
  #pragma unroll
  for (int m = 0; m < 2; ++m) {
    #pragma unroll
    for (int n = 0; n < 8; ++n) {
      const int d = wc * 128 + n * 16 + lr;
      const int row = wr * 32 + m * 16 + lg * 4;
      #pragma unroll
      for (int r = 0; r < 4; ++r) {
        const size_t off = ((size_t)b * 256 + row + r) * 256 + d;
        out[off] = acc[m][n][r] + bf2f((unsigned short)P2[off]);
      }
    }
  }
}

extern "C" void kernel_launch(void* const* d_in, const int* in_sizes, int n_in,
                              void* d_out, int out_size, void* d_ws, size_t ws_size,
                              hipStream_t stream) {
  const float* hidden  = (const float*)d_in[0];
  const float* dist    = (const float*)d_in[1];
  const float* bear    = (const float*)d_in[2];
  const float* head    = (const float*)d_in[3];
  const float* seqmask = (const float*)d_in[4];
  const float* domain  = (const float*)d_in[5];
  const float* W       = (const float*)d_in[6];
  const float* bias    = (const float*)d_in[7];
  float* out = (float*)d_out;

  char* ws = (char*)d_ws;
  short* Wbf   = (short*)ws;                                 // 512 KB
  float* flag  = (float*)(ws + 524288);                      // 2 floats
  short* P1T   = (short*)(ws + (1u << 20));                  // 32 MB
  short* P2    = (short*)(ws + (1u << 20) + (32u << 20));    // 32 MB
  short* weBuf = (short*)(ws + (1u << 20) + (64u << 20));    // 32 MB

  k0_pack<<<128, 256, 0, stream>>>(W, Wbf);
  k0_check<<<1, 256, 0, stream>>>(domain, flag);
  k2a_weights<<<2048, 256, 0, stream>>>(dist, bear, head, seqmask, domain, flag, weBuf);
  kP<<<256, 1024, 131072, stream>>>(hidden, Wbf, bias, P1T, P2);
  kOut<<<256, 1024, 131072, stream>>>(weBuf, P1T, P2, out);
}

// Round 21
// 126.847 us; speedup vs baseline: 1.3755x; 1.3755x over previous
//
#include <hip/hip_runtime.h>
#include <hip/hip_bf16.h>

// spatial_attention: out = softmax_weights @ (H W1^T) + H @ W2^T + bias
//   Domain uniform (runtime-verified) -> weights fast path: w = relu(dval - dist).
//   Base = R18 (best, 107.7us). Change: k2a FUSED into k2b — weight numerators
//   computed in A-fragment registers (R4/R6-verified math), rs shfl-reduced over
//   lg, acc scaled between GEMM halves. Deletes k2a dispatch + weBuf 64MB traffic.
//   K0    : Wbf = bf16(W); k0_check -> {dval, uniform}
//   k1_p1t: P1T[b][d][j] = bf16((H W1^T)^T)  (R18-proven, 42us)
//   k2b   : g=0-3: weights(regs) @ P1T ; scale ; g=4-7: bf16(H) @ W2 ; +bias
// Workspace: Wbf 512KB @0 ; flag @512KB ; P1T 32MB @1MB

typedef __attribute__((ext_vector_type(4))) float  f32x4;
typedef __attribute__((ext_vector_type(8))) short  bf16x8;
typedef __attribute__((ext_vector_type(4))) short  bf16x4;

#define EPSC 1e-14f

__device__ __forceinline__ short f2bf(float v) {
  __hip_bfloat16 h = __float2bfloat16(v);
  return *reinterpret_cast<short*>(&h);
}
__device__ __forceinline__ void gload16(const void* g, void* l) {
  __builtin_amdgcn_global_load_lds(
      (const __attribute__((address_space(1))) void*)g,
      (__attribute__((address_space(3))) void*)l, 16, 0, 0);
}
__device__ __forceinline__ bf16x8 cvt8(const float* p) {
  f32x4 a = *(const f32x4*)p;
  f32x4 b = *(const f32x4*)(p + 4);
  bf16x8 r;
  r[0] = f2bf(a[0]); r[1] = f2bf(a[1]); r[2] = f2bf(a[2]); r[3] = f2bf(a[3]);
  r[4] = f2bf(b[0]); r[5] = f2bf(b[1]); r[6] = f2bf(b[2]); r[7] = f2bf(b[3]);
  return r;
}
// weight numerators for 8 js (uniform-domain fast path); rs accumulates row sum
__device__ __forceinline__ bf16x8 pack8(
    f32x4 da, f32x4 db, f32x4 ma, f32x4 mb,
    int gk, int i, float mI, float dval, float& rs) {
  bf16x8 pk;
  #pragma unroll
  for (int e = 0; e < 4; ++e) {
    float wv = fmaxf(dval - da[e], 0.f);
    bool valid = (i != gk + e) && (mI != 0.f) && (ma[e] != 0.f);
    float ex = (wv > 0.f) ? __expf(wv) : 0.f;
    ex = valid ? ex : 0.f;
    rs += ex;
    pk[e] = f2bf(valid ? (ex + EPSC) : 0.f);
  }
  #pragma unroll
  for (int e = 0; e < 4; ++e) {
    float wv = fmaxf(dval - db[e], 0.f);
    bool valid = (i != gk + 4 + e) && (mI != 0.f) && (mb[e] != 0.f);
    float ex = (wv > 0.f) ? __expf(wv) : 0.f;
    ex = valid ? ex : 0.f;
    rs += ex;
    pk[4 + e] = f2bf(valid ? (ex + EPSC) : 0.f);
  }
  return pk;
}
// gather fallback (non-uniform domain; correctness only)
__device__ __forceinline__ bf16x8 pack8g(
    const float* __restrict__ dist, const float* __restrict__ bear,
    const float* __restrict__ head, const float* __restrict__ domain,
    f32x4 ma, f32x4 mb, size_t base, int gk, int i, float mI, float& rs) {
  f32x4 d0 = *(const f32x4*)(dist + base + gk);
  f32x4 d1 = *(const f32x4*)(dist + base + gk + 4);
  f32x4 b0 = *(const f32x4*)(bear + base + gk);
  f32x4 b1 = *(const f32x4*)(bear + base + gk + 4);
  f32x4 h0 = *(const f32x4*)(head + base + gk);
  f32x4 h1 = *(const f32x4*)(head + base + gk + 4);
  bf16x8 pk;
  #pragma unroll
  for (int e = 0; e < 4; ++e) {
    float f1 = fminf(fmaxf(floorf((h0[e] + 2.5f) * 0.2f), 0.f), 71.f);
    float f2 = fminf(fmaxf(floorf((b0[e] + 2.5f) * 0.2f), 0.f), 71.f);
    float wv = fmaxf(domain[(int)(f1 * 72.f + f2)] - d0[e], 0.f);
    bool valid = (i != gk + e) && (mI != 0.f) && (ma[e] != 0.f);
    float ex = (wv > 0.f) ? __expf(wv) : 0.f;
    ex = valid ? ex : 0.f;
    rs += ex;
    pk[e] = f2bf(valid ? (ex + EPSC) : 0.f);
  }
  #pragma unroll
  for (int e = 0; e < 4; ++e) {
    float f1 = fminf(fmaxf(floorf((h1[e] + 2.5f) * 0.2f), 0.f), 71.f);
    float f2 = fminf(fmaxf(floorf((b1[e] + 2.5f) * 0.2f), 0.f), 71.f);
    float wv = fmaxf(domain[(int)(f1 * 72.f + f2)] - d1[e], 0.f);
    bool valid = (i != gk + 4 + e) && (mI != 0.f) && (mb[e] != 0.f);
    float ex = (wv > 0.f) ? __expf(wv) : 0.f;
    ex = valid ? ex : 0.f;
    rs += ex;
    pk[4 + e] = f2bf(valid ? (ex + EPSC) : 0.f);
  }
  return pk;
}

// ---------------- K0: W fp32 -> bf16 ----------------
__global__ void k0_pack(const float* __restrict__ W, short* __restrict__ Wbf) {
  int idx = blockIdx.x * 256 + threadIdx.x;
  f32x4 v = *(const f32x4*)(W + (size_t)idx * 4);
  bf16x4 pk;
  pk[0] = f2bf(v[0]); pk[1] = f2bf(v[1]); pk[2] = f2bf(v[2]); pk[3] = f2bf(v[3]);
  *(bf16x4*)(Wbf + (size_t)idx * 4) = pk;
}

// ---------------- K0b: domain uniformity check ----------------
__global__ void k0_check(const float* __restrict__ domain, float* __restrict__ flag) {
  __shared__ int s_ok[4];
  const int t = threadIdx.x;
  float v0 = domain[0];
  bool ok = true;
  for (int x = t; x < 72 * 72; x += 256) ok = ok && (domain[x] == v0);
  unsigned long long m = __ballot(ok);
  if ((t & 63) == 0) s_ok[t >> 6] = (m == ~0ull) ? 1 : 0;
  __syncthreads();
  if (t == 0) {
    flag[0] = v0;
    flag[1] = (s_ok[0] && s_ok[1] && s_ok[2] && s_ok[3]) ? 1.f : 0.f;
  }
}

// ---------------- k1_p1t: P1T = (H W1^T)^T, FAT 128-row blocks, dbuf (R18) ----------------
__global__ __launch_bounds__(512, 4) void k1_p1t(
    const float* __restrict__ H, const short* __restrict__ Wbf,
    short* __restrict__ P1T) {
  extern __shared__ char sm[];
  char* sB0 = sm;
  char* sB1 = sm + 32768;
  const int t = threadIdx.x;
  const int x = blockIdx.x;
  const int blk = (x & 7) * 64 + (x >> 3);     // bijective: 512 = 8*64
  const int n0 = blk * 128;
  const int b  = n0 >> 8;
  const int jb = n0 & 255;

  const int wid = t >> 6, l = t & 63;
  const int lr = l & 15, lg = l >> 4;
  const int wr = wid & 3, wc = wid >> 2;
  const int r3 = l >> 3, sl = l & 7;
  const int sswz = (sl ^ r3) * 8;
  const int sw = (lr & 7) << 4;

  const size_t h0 = ((size_t)(n0 + wr * 32 + lr)) * 256;
  const size_t h1 = h0 + 16 * 256;

  #pragma unroll
  for (int p = 0; p < 4; ++p) {
    int dd = wid * 8 + r3 + 64 * p;
    gload16(Wbf + (size_t)dd * 512 + sswz, sB0 + (wid * 8 + 64 * p) * 128);
  }
  __syncthreads();

  f32x4 acc[2][8] = {};

  #pragma unroll
  for (int c = 0; c < 4; ++c) {
    char* cur = (c & 1) ? sB1 : sB0;
    char* nxt = (c & 1) ? sB0 : sB1;
    if (c < 3) {
      #pragma unroll
      for (int p = 0; p < 4; ++p) {
        int dd = wid * 8 + r3 + 64 * p;
        gload16(Wbf + (size_t)dd * 512 + (c + 1) * 64 + sswz, nxt + (wid * 8 + 64 * p) * 128);
      }
    }
    const int kk = c * 64;
    #pragma unroll
    for (int sub = 0; sub < 2; ++sub) {
      bf16x8 av0 = cvt8(H + h0 + kk + sub * 32 + lg * 8);
      bf16x8 av1 = cvt8(H + h1 + kk + sub * 32 + lg * 8);
      #pragma unroll
      for (int n = 0; n < 8; ++n) {
        const int d = wc * 128 + n * 16 + lr;
        bf16x8 bb = *(const bf16x8*)(cur + d * 128 + ((sub * 64 + lg * 16) ^ sw));
        acc[0][n] = __builtin_amdgcn_mfma_f32_16x16x32_bf16(av0, bb, acc[0][n], 0, 0, 0);
        acc[1][n] = __builtin_amdgcn_mfma_f32_16x16x32_bf16(av1, bb, acc[1][n], 0, 0, 0);
      }
    }
    __syncthreads();
  }

  #pragma unroll
  for (int m = 0; m < 2; ++m) {
    #pragma unroll
    for (int n = 0; n < 8; ++n) {
      const int d = wc * 128 + n * 16 + lr;
      f32x4 v = acc[m][n];
      bf16x4 pk;
      pk[0] = f2bf(v[0]); pk[1] = f2bf(v[1]); pk[2] = f2bf(v[2]); pk[3] = f2bf(v[3]);
      *(bf16x4*)(P1T + (size_t)b * 65536 + (size_t)d * 256 + jb + wr * 32 + m * 16 + lg * 4) = pk;
    }
  }
}

// ---------------- k2b: out = weights @ P1T + bf16(H) @ W2 + bias, FUSED ----------------
// R18 skeleton: grid 512 (XCD-swizzled), block 512, dbuf 2x32KB, 8 chunks.
// g=0-3: A = weight numerators in regs (dist+mask), B = P1T gload16; rs accumulated.
// after g=3: rs shfl-reduce over lg, acc *= 1/(rs+257eps).
// g=4-7: A = H per-thread cvt, B = W2 gload16. Epilogue +bias.
// LDS: sB0 32768 + sB1 32768 + mask 1024 + bias 1024 = 67584 -> 2 blocks/CU.
__global__ __launch_bounds__(512, 4) void k2b_fused(
    const float* __restrict__ dist, const float* __restrict__ bear,
    const float* __restrict__ head, const float* __restrict__ seqmask,
    const float* __restrict__ domain, const float* __restrict__ uflag,
    const short* __restrict__ P1T, const short* __restrict__ Wbf,
    const float* __restrict__ H, const float* __restrict__ bias,
    float* __restrict__ out) {
  extern __shared__ char sm[];
  char*  sB0   = sm;
  char*  sB1   = sm + 32768;
  float* sMask = (float*)(sm + 65536);
  float* sBias = (float*)(sm + 66560);
  const int t = threadIdx.x;
  const int x = blockIdx.x;
  const int blk = (x & 7) * 64 + (x >> 3);     // bijective: 512 = 8*64
  const int b  = blk >> 1;
  const int i0 = (blk & 1) * 128;

  const int wid = t >> 6, l = t & 63;
  const int lr = l & 15, lg = l >> 4;
  const int wr = wid & 3, wc = wid >> 2;
  const int r3 = l >> 3, sl = l & 7;
  const int sswz = (sl ^ r3) * 8;
  const int sw = (lr & 7) << 4;

  const short* __restrict__ P1b = P1T + (size_t)b * 65536;
  const int i_a0 = i0 + wr * 32 + lr;          // this thread's two weight rows
  const int i_a1 = i_a0 + 16;
  const size_t base0 = ((size_t)b * 256 + i_a0) * 256;
  const size_t base1 = base0 + 16 * 256;

  const float dval = uflag[0];
  const bool  uni  = uflag[1] != 0.f;

  // prologue: stage chunk 0 (P1T kk=0) + mask + bias
  #pragma unroll
  for (int p = 0; p < 4; ++p) {
    int dd = wid * 8 + r3 + 64 * p;
    gload16(P1b + (size_t)dd * 256 + sswz, sB0 + (wid * 8 + 64 * p) * 128);
  }
  if (t < 256) { sMask[t] = seqmask[b * 256 + t]; sBias[t] = bias[t]; }
  __syncthreads();

  const float mI0 = sMask[i_a0];
  const float mI1 = sMask[i_a1];

  f32x4 acc[2][8] = {};
  float rs0 = 0.f, rs1 = 0.f;

  #pragma unroll
  for (int g = 0; g < 8; ++g) {
    char* cur = (g & 1) ? sB1 : sB0;
    char* nxt = (g & 1) ? sB0 : sB1;
    if (g < 7) {                       // issue next chunk BEFORE compute
      const int nk = ((g + 1) & 3) * 64;
      if (g + 1 < 4) {
        #pragma unroll
        for (int p = 0; p < 4; ++p) {
          int dd = wid * 8 + r3 + 64 * p;
          gload16(P1b + (size_t)dd * 256 + nk + sswz, nxt + (wid * 8 + 64 * p) * 128);
        }
      } else {
        #pragma unroll
        for (int p = 0; p < 4; ++p) {
          int dd = wid * 8 + r3 + 64 * p;
          gload16(Wbf + (size_t)dd * 512 + 256 + nk + sswz, nxt + (wid * 8 + 64 * p) * 128);
        }
      }
    }
    const int kk = (g & 3) * 64;
    #pragma unroll
    for (int sub = 0; sub < 2; ++sub) {
      const int k0 = kk + sub * 32 + lg * 8;
      bf16x8 av0, av1;
      if (g < 4) {
        f32x4 m0 = *(const f32x4*)(sMask + k0);
        f32x4 m1 = *(const f32x4*)(sMask + k0 + 4);
        if (uni) {
          f32x4 d0 = *(const f32x4*)(dist + base0 + k0);
          f32x4 d1 = *(const f32x4*)(dist + base0 + k0 + 4);
          f32x4 d2 = *(const f32x4*)(dist + base1 + k0);
          f32x4 d3 = *(const f32x4*)(dist + base1 + k0 + 4);
          av0 = pack8(d0, d1, m0, m1, k0, i_a0, mI0, dval, rs0);
          av1 = pack8(d2, d3, m0, m1, k0, i_a1, mI1, dval, rs1);
        } else {
          av0 = pack8g(dist, bear, head, domain, m0, m1, base0, k0, i_a0, mI0, rs0);
          av1 = pack8g(dist, bear, head, domain, m0, m1, base1, k0, i_a1, mI1, rs1);
        }
      } else {
        av0 = cvt8(H + base0 + k0);
        av1 = cvt8(H + base1 + k0);
      }
      #pragma unroll
      for (int n = 0; n < 8; ++n) {
        const int d = wc * 128 + n * 16 + lr;
        bf16x8 bb = *(const bf16x8*)(cur + d * 128 + ((sub * 64 + lg * 16) ^ sw));
        acc[0][n] = __builtin_amdgcn_mfma_f32_16x16x32_bf16(av0, bb, acc[0][n], 0, 0, 0);
        acc[1][n] = __builtin_amdgcn_mfma_f32_16x16x32_bf16(av1, bb, acc[1][n], 0, 0, 0);
      }
    }
    if (g == 3) {
      // row-sum reduce across lg lanes; scale acc (weights half complete)
      rs0 += __shfl_xor(rs0, 16, 64); rs0 += __shfl_xor(rs0, 32, 64);
      rs1 += __shfl_xor(rs1, 16, 64); rs1 += __shfl_xor(rs1, 32, 64);
      const float sc0 = 1.0f / (rs0 + 257.0f * EPSC);
      const float sc1 = 1.0f / (rs1 + 257.0f * EPSC);
      float srow[2][4];
      #pragma unroll
      for (int r = 0; r < 4; ++r) {
        srow[0][r] = __shfl(sc0, lg * 4 + r, 64);
        srow[1][r] = __shfl(sc1, lg * 4 + r, 64);
      }
      #pragma unroll
      for (int m = 0; m < 2; ++m)
        #pragma unroll
        for (int n = 0; n < 8; ++n) {
          acc[m][n][0] *= srow[m][0]; acc[m][n][1] *= srow[m][1];
          acc[m][n][2] *= srow[m][2]; acc[m][n][3] *= srow[m][3];
        }
    }
    __syncthreads();
  }

  // epilogue: + bias, fp32 store
  #pragma unroll
  for (int m = 0; m < 2; ++m) {
    #pragma unroll
    for (int n = 0; n < 8; ++n) {
      const int d = wc * 128 + n * 16 + lr;
      const float bs = sBias[d];
      #pragma unroll
      for (int r = 0; r < 4; ++r) {
        const int row = i0 + wr * 32 + m * 16 + lg * 4 + r;
        out[((size_t)b * 256 + row) * 256 + d] = acc[m][n][r] + bs;
      }
    }
  }
}

extern "C" void kernel_launch(void* const* d_in, const int* in_sizes, int n_in,
                              void* d_out, int out_size, void* d_ws, size_t ws_size,
                              hipStream_t stream) {
  const float* hidden  = (const float*)d_in[0];
  const float* dist    = (const float*)d_in[1];
  const float* bear    = (const float*)d_in[2];
  const float* head    = (const float*)d_in[3];
  const float* seqmask = (const float*)d_in[4];
  const float* domain  = (const float*)d_in[5];
  const float* W       = (const float*)d_in[6];
  const float* bias    = (const float*)d_in[7];
  float* out = (float*)d_out;

  char* ws = (char*)d_ws;
  short* Wbf  = (short*)ws;                                  // 512 KB
  float* flag = (float*)(ws + 524288);                       // 2 floats
  short* P1T  = (short*)(ws + (1u << 20));                   // 32 MB

  k0_pack<<<128, 256, 0, stream>>>(W, Wbf);
  k0_check<<<1, 256, 0, stream>>>(domain, flag);
  k1_p1t<<<512, 512, 65536, stream>>>(hidden, Wbf, P1T);
  k2b_fused<<<512, 512, 67584, stream>>>(dist, bear, head, seqmask, domain, flag,
                                         P1T, Wbf, hidden, bias, out);
}

// Round 22
// 108.747 us; speedup vs baseline: 1.6045x; 1.1664x over previous
//
#include <hip/hip_runtime.h>
#include <hip/hip_bf16.h>

// spatial_attention: out = weights @ P1 + H @ W2^T + bias ; P1 = H W1^T
//   Domain uniform (runtime-verified) -> weights fast path: w = relu(dval - dist).
//   Base = R18 (best, 107.7us). Change: k2a merged into k1 as a SAME-BLOCK PHASE
//   (weights for the block's own 128 rows computed wave-per-row BEFORE the GEMM
//   loop; temporaries die before acc goes live -> no R21 spill mechanism; the
//   weight phase's dist stream overlaps the co-resident block's GEMM stalls).
//   K0  : Wbf = bf16(W); k0_check -> {dval, uniform}
//   kAll: phase 1: weights rows [n0, n0+128) -> weBuf ; phase 2: P1T GEMM (R18)
//   k2b : out = weBuf @ P1T (g=0-3) + bf16(H) @ W2 (g=4-7) + bias (R18 verbatim)
// Workspace: Wbf 512KB @0 ; flag @512KB ; P1T 32MB @1MB ; weBuf 32MB @33MB

typedef __attribute__((ext_vector_type(4))) float  f32x4;
typedef __attribute__((ext_vector_type(8))) short  bf16x8;
typedef __attribute__((ext_vector_type(4))) short  bf16x4;

#define EPSC 1e-14f

__device__ __forceinline__ short f2bf(float v) {
  __hip_bfloat16 h = __float2bfloat16(v);
  return *reinterpret_cast<short*>(&h);
}
__device__ __forceinline__ void gload16(const void* g, void* l) {
  __builtin_amdgcn_global_load_lds(
      (const __attribute__((address_space(1))) void*)g,
      (__attribute__((address_space(3))) void*)l, 16, 0, 0);
}
__device__ __forceinline__ bf16x8 cvt8(const float* p) {
  f32x4 a = *(const f32x4*)p;
  f32x4 b = *(const f32x4*)(p + 4);
  bf16x8 r;
  r[0] = f2bf(a[0]); r[1] = f2bf(a[1]); r[2] = f2bf(a[2]); r[3] = f2bf(a[3]);
  r[4] = f2bf(b[0]); r[5] = f2bf(b[1]); r[6] = f2bf(b[2]); r[7] = f2bf(b[3]);
  return r;
}

// ---------------- K0: W fp32 -> bf16 ----------------
__global__ void k0_pack(const float* __restrict__ W, short* __restrict__ Wbf) {
  int idx = blockIdx.x * 256 + threadIdx.x;
  f32x4 v = *(const f32x4*)(W + (size_t)idx * 4);
  bf16x4 pk;
  pk[0] = f2bf(v[0]); pk[1] = f2bf(v[1]); pk[2] = f2bf(v[2]); pk[3] = f2bf(v[3]);
  *(bf16x4*)(Wbf + (size_t)idx * 4) = pk;
}

// ---------------- K0b: domain uniformity check ----------------
__global__ void k0_check(const float* __restrict__ domain, float* __restrict__ flag) {
  __shared__ int s_ok[4];
  const int t = threadIdx.x;
  float v0 = domain[0];
  bool ok = true;
  for (int x = t; x < 72 * 72; x += 256) ok = ok && (domain[x] == v0);
  unsigned long long m = __ballot(ok);
  if ((t & 63) == 0) s_ok[t >> 6] = (m == ~0ull) ? 1 : 0;
  __syncthreads();
  if (t == 0) {
    flag[0] = v0;
    flag[1] = (s_ok[0] && s_ok[1] && s_ok[2] && s_ok[3]) ? 1.f : 0.f;
  }
}

// ---------------- kAll: weights phase + P1T GEMM, FAT 128-row blocks ----------------
// grid 512 (XCD-swizzled), block 512, LDS 66560 -> 2 blocks/CU.
// Phase 1: this block's 128 rows of pre-scaled weights -> weBuf (wave-per-row,
//          8 waves x 16 rows, R9-proven; temps die before phase 2).
// Phase 2: P1T[b][d][j] = bf16((H W1^T)^T), R18 dbuf gload16 skeleton.
__global__ __launch_bounds__(512, 4) void kAll(
    const float* __restrict__ H, const short* __restrict__ Wbf,
    const float* __restrict__ dist, const float* __restrict__ bear,
    const float* __restrict__ head, const float* __restrict__ seqmask,
    const float* __restrict__ domain, const float* __restrict__ uflag,
    short* __restrict__ P1T, short* __restrict__ weBuf) {
  extern __shared__ char sm[];
  char*  sB0   = sm;
  char*  sB1   = sm + 32768;
  float* sMask = (float*)(sm + 65536);
  const int t = threadIdx.x;
  const int x = blockIdx.x;
  const int blk = (x & 7) * 64 + (x >> 3);     // bijective: 512 = 8*64
  const int n0 = blk * 128;
  const int b  = n0 >> 8;
  const int jb = n0 & 255;

  const int wid = t >> 6, l = t & 63;
  const int lr = l & 15, lg = l >> 4;
  const int wr = wid & 3, wc = wid >> 2;
  const int r3 = l >> 3, sl = l & 7;
  const int sswz = (sl ^ r3) * 8;
  const int sw = (lr & 7) << 4;

  // issue chunk-0 staging first (lands while weight phase runs)
  #pragma unroll
  for (int p = 0; p < 4; ++p) {
    int dd = wid * 8 + r3 + 64 * p;
    gload16(Wbf + (size_t)dd * 512 + sswz, sB0 + (wid * 8 + 64 * p) * 128);
  }
  if (t < 256) sMask[t] = seqmask[b * 256 + t];
  __syncthreads();                             // mask + chunk0 visible

  // ================= phase 1: weights for rows [n0+wid*16, +16) =================
  {
    const int j0 = l * 4;
    const float dval = uflag[0];
    const bool  uni  = uflag[1] != 0.f;
    const f32x4 mj = *(const f32x4*)(sMask + j0);
    const int rbase = (n0 & 255) + wid * 16;   // row offset within batch

    #pragma unroll
    for (int half = 0; half < 2; ++half) {
      f32x4 dv[8];
      #pragma unroll
      for (int rr = 0; rr < 8; ++rr) {
        int i = rbase + half * 8 + rr;
        dv[rr] = *(const f32x4*)(dist + ((size_t)b * 256 + i) * 256 + j0);
      }
      #pragma unroll
      for (int rr = 0; rr < 8; ++rr) {
        const int i = rbase + half * 8 + rr;
        const float mI = sMask[i];
        const size_t base = ((size_t)b * 256 + i) * 256;
        float ev[4];
        float rs = 0.f;
        if (uni) {
          #pragma unroll
          for (int e = 0; e < 4; ++e) {
            float wv = fmaxf(dval - dv[rr][e], 0.f);
            bool valid = (i != j0 + e) && (mI != 0.f) && (mj[e] != 0.f);
            float ex = (wv > 0.f) ? __expf(wv) : 0.f;
            ex = valid ? ex : 0.f;
            rs += ex;
            ev[e] = valid ? (ex + EPSC) : 0.f;
          }
        } else {
          f32x4 bv = *(const f32x4*)(bear + base + j0);
          f32x4 hv = *(const f32x4*)(head + base + j0);
          #pragma unroll
          for (int e = 0; e < 4; ++e) {
            float f1 = fminf(fmaxf(floorf((hv[e] + 2.5f) * 0.2f), 0.f), 71.f);
            float f2 = fminf(fmaxf(floorf((bv[e] + 2.5f) * 0.2f), 0.f), 71.f);
            float wv = fmaxf(domain[(int)(f1 * 72.f + f2)] - dv[rr][e], 0.f);
            bool valid = (i != j0 + e) && (mI != 0.f) && (mj[e] != 0.f);
            float ex = (wv > 0.f) ? __expf(wv) : 0.f;
            ex = valid ? ex : 0.f;
            rs += ex;
            ev[e] = valid ? (ex + EPSC) : 0.f;
          }
        }
        rs += __shfl_xor(rs, 1, 64);
        rs += __shfl_xor(rs, 2, 64);
        rs += __shfl_xor(rs, 4, 64);
        rs += __shfl_xor(rs, 8, 64);
        rs += __shfl_xor(rs, 16, 64);
        rs += __shfl_xor(rs, 32, 64);
        const float scale = 1.0f / (rs + 257.0f * EPSC);
        bf16x4 pk;
        pk[0] = f2bf(ev[0] * scale); pk[1] = f2bf(ev[1] * scale);
        pk[2] = f2bf(ev[2] * scale); pk[3] = f2bf(ev[3] * scale);
        *(bf16x4*)(weBuf + base + j0) = pk;
      }
    }
  }

  // ================= phase 2: P1T GEMM (R18 verbatim) =================
  const size_t h0 = ((size_t)(n0 + wr * 32 + lr)) * 256;
  const size_t h1 = h0 + 16 * 256;

  f32x4 acc[2][8] = {};

  #pragma unroll
  for (int c = 0; c < 4; ++c) {
    char* cur = (c & 1) ? sB1 : sB0;
    char* nxt = (c & 1) ? sB0 : sB1;
    if (c < 3) {
      #pragma unroll
      for (int p = 0; p < 4; ++p) {
        int dd = wid * 8 + r3 + 64 * p;
        gload16(Wbf + (size_t)dd * 512 + (c + 1) * 64 + sswz, nxt + (wid * 8 + 64 * p) * 128);
      }
    }
    const int kk = c * 64;
    #pragma unroll
    for (int sub = 0; sub < 2; ++sub) {
      bf16x8 av0 = cvt8(H + h0 + kk + sub * 32 + lg * 8);
      bf16x8 av1 = cvt8(H + h1 + kk + sub * 32 + lg * 8);
      #pragma unroll
      for (int n = 0; n < 8; ++n) {
        const int d = wc * 128 + n * 16 + lr;
        bf16x8 bb = *(const bf16x8*)(cur + d * 128 + ((sub * 64 + lg * 16) ^ sw));
        acc[0][n] = __builtin_amdgcn_mfma_f32_16x16x32_bf16(av0, bb, acc[0][n], 0, 0, 0);
        acc[1][n] = __builtin_amdgcn_mfma_f32_16x16x32_bf16(av1, bb, acc[1][n], 0, 0, 0);
      }
    }
    __syncthreads();
  }

  #pragma unroll
  for (int m = 0; m < 2; ++m) {
    #pragma unroll
    for (int n = 0; n < 8; ++n) {
      const int d = wc * 128 + n * 16 + lr;
      f32x4 v = acc[m][n];
      bf16x4 pk;
      pk[0] = f2bf(v[0]); pk[1] = f2bf(v[1]); pk[2] = f2bf(v[2]); pk[3] = f2bf(v[3]);
      *(bf16x4*)(P1T + (size_t)b * 65536 + (size_t)d * 256 + jb + wr * 32 + m * 16 + lg * 4) = pk;
    }
  }
}

// ---------------- k2b: out = weBuf @ P1T + bf16(H) @ W2 + bias (R18 verbatim) ----------------
__global__ __launch_bounds__(512, 4) void k2b_gemm(
    const short* __restrict__ weBuf, const short* __restrict__ P1T,
    const short* __restrict__ Wbf, const float* __restrict__ H,
    const float* __restrict__ bias, float* __restrict__ out) {
  extern __shared__ char sm[];
  char*  sB0   = sm;
  char*  sB1   = sm + 32768;
  float* sBias = (float*)(sm + 65536);
  const int t = threadIdx.x;
  const int x = blockIdx.x;
  const int blk = (x & 7) * 64 + (x >> 3);     // bijective: 512 = 8*64
  const int b  = blk >> 1;
  const int i0 = (blk & 1) * 128;

  const int wid = t >> 6, l = t & 63;
  const int lr = l & 15, lg = l >> 4;
  const int wr = wid & 3, wc = wid >> 2;
  const int r3 = l >> 3, sl = l & 7;
  const int sswz = (sl ^ r3) * 8;
  const int sw = (lr & 7) << 4;

  const short* __restrict__ P1b = P1T + (size_t)b * 65536;
  const size_t a0 = ((size_t)b * 256 + i0 + wr * 32 + lr) * 256;
  const size_t a1 = a0 + 16 * 256;

  #pragma unroll
  for (int p = 0; p < 4; ++p) {
    int dd = wid * 8 + r3 + 64 * p;
    gload16(P1b + (size_t)dd * 256 + sswz, sB0 + (wid * 8 + 64 * p) * 128);
  }
  if (t < 256) sBias[t] = bias[t];
  __syncthreads();

  f32x4 acc[2][8] = {};

  #pragma unroll
  for (int g = 0; g < 8; ++g) {
    char* cur = (g & 1) ? sB1 : sB0;
    char* nxt = (g & 1) ? sB0 : sB1;
    if (g < 7) {
      const int nk = ((g + 1) & 3) * 64;
      if (g + 1 < 4) {
        #pragma unroll
        for (int p = 0; p < 4; ++p) {
          int dd = wid * 8 + r3 + 64 * p;
          gload16(P1b + (size_t)dd * 256 + nk + sswz, nxt + (wid * 8 + 64 * p) * 128);
        }
      } else {
        #pragma unroll
        for (int p = 0; p < 4; ++p) {
          int dd = wid * 8 + r3 + 64 * p;
          gload16(Wbf + (size_t)dd * 512 + 256 + nk + sswz, nxt + (wid * 8 + 64 * p) * 128);
        }
      }
    }
    const int kk = (g & 3) * 64;
    #pragma unroll
    for (int sub = 0; sub < 2; ++sub) {
      bf16x8 av0, av1;
      if (g < 4) {
        av0 = *(const bf16x8*)(weBuf + a0 + kk + sub * 32 + lg * 8);
        av1 = *(const bf16x8*)(weBuf + a1 + kk + sub * 32 + lg * 8);
      } else {
        av0 = cvt8(H + a0 + kk + sub * 32 + lg * 8);
        av1 = cvt8(H + a1 + kk + sub * 32 + lg * 8);
      }
      #pragma unroll
      for (int n = 0; n < 8; ++n) {
        const int d = wc * 128 + n * 16 + lr;
        bf16x8 bb = *(const bf16x8*)(cur + d * 128 + ((sub * 64 + lg * 16) ^ sw));
        acc[0][n] = __builtin_amdgcn_mfma_f32_16x16x32_bf16(av0, bb, acc[0][n], 0, 0, 0);
        acc[1][n] = __builtin_amdgcn_mfma_f32_16x16x32_bf16(av1, bb, acc[1][n], 0, 0, 0);
      }
    }
    __syncthreads();
  }

  #pragma unroll
  for (int m = 0; m < 2; ++m) {
    #pragma unroll
    for (int n = 0; n < 8; ++n) {
      const int d = wc * 128 + n * 16 + lr;
      const float bs = sBias[d];
      #pragma unroll
      for (int r = 0; r < 4; ++r) {
        const int row = i0 + wr * 32 + m * 16 + lg * 4 + r;
        out[((size_t)b * 256 + row) * 256 + d] = acc[m][n][r] + bs;
      }
    }
  }
}

extern "C" void kernel_launch(void* const* d_in, const int* in_sizes, int n_in,
                              void* d_out, int out_size, void* d_ws, size_t ws_size,
                              hipStream_t stream) {
  const float* hidden  = (const float*)d_in[0];
  const float* dist    = (const float*)d_in[1];
  const float* bear    = (const float*)d_in[2];
  const float* head    = (const float*)d_in[3];
  const float* seqmask = (const float*)d_in[4];
  const float* domain  = (const float*)d_in[5];
  const float* W       = (const float*)d_in[6];
  const float* bias    = (const float*)d_in[7];
  float* out = (float*)d_out;

  char* ws = (char*)d_ws;
  short* Wbf   = (short*)ws;                                 // 512 KB
  float* flag  = (float*)(ws + 524288);                      // 2 floats
  short* P1T   = (short*)(ws + (1u << 20));                  // 32 MB
  short* weBuf = (short*)(ws + (1u << 20) + (32u << 20));    // 32 MB

  k0_pack<<<128, 256, 0, stream>>>(W, Wbf);
  k0_check<<<1, 256, 0, stream>>>(domain, flag);
  kAll<<<512, 512, 66560, stream>>>(hidden, Wbf, dist, bear, head, seqmask,
                                    domain, flag, P1T, weBuf);
  k2b_gemm<<<512, 512, 66560, stream>>>(weBuf, P1T, Wbf, hidden, bias, out);
}

// Round 23
// 106.959 us; speedup vs baseline: 1.6313x; 1.0167x over previous
//
#include <hip/hip_runtime.h>
#include <hip/hip_bf16.h>

// spatial_attention: out = weights @ P1 + H @ W2^T + bias ; P1 = H W1^T
//   Domain uniform (runtime-verified) -> weights fast path: w = relu(dval - dist).
//   Base = R18 (best, 107.7us). Change: GEMM K-loops restructured into BIG
//   barrier-free spans — stage 64KB of B (two R18-format 32KB regions) at once,
//   then 4 MFMA-subs with no barriers (compiler hoists A-loads freely).
//   k1: 3 barriers total (was 8). k2b: 8 barriers but 2x longer free spans.
//   K0  : Wbf = bf16(W); k0_check -> {dval, uniform}
//   k2a : weights -> weBuf (pre-scaled bf16), wave-per-row (R9-proven, ~BW floor)
//   k1  : P1T[b][d][j] = bf16((H W1^T)^T), fat 128-row blocks, grid 512
//   k2b : out = weBuf @ P1T + bf16(H) @ W2 + bias, K=512, grid 512
// Workspace: Wbf 512KB @0 ; flag @512KB ; P1T 32MB @1MB ; weBuf 32MB @33MB

typedef __attribute__((ext_vector_type(4))) float  f32x4;
typedef __attribute__((ext_vector_type(8))) short  bf16x8;
typedef __attribute__((ext_vector_type(4))) short  bf16x4;

#define EPSC 1e-14f

__device__ __forceinline__ short f2bf(float v) {
  __hip_bfloat16 h = __float2bfloat16(v);
  return *reinterpret_cast<short*>(&h);
}
__device__ __forceinline__ void gload16(const void* g, void* l) {
  __builtin_amdgcn_global_load_lds(
      (const __attribute__((address_space(1))) void*)g,
      (__attribute__((address_space(3))) void*)l, 16, 0, 0);
}
__device__ __forceinline__ bf16x8 cvt8(const float* p) {
  f32x4 a = *(const f32x4*)p;
  f32x4 b = *(const f32x4*)(p + 4);
  bf16x8 r;
  r[0] = f2bf(a[0]); r[1] = f2bf(a[1]); r[2] = f2bf(a[2]); r[3] = f2bf(a[3]);
  r[4] = f2bf(b[0]); r[5] = f2bf(b[1]); r[6] = f2bf(b[2]); r[7] = f2bf(b[3]);
  return r;
}

// ---------------- K0: W fp32 -> bf16 ----------------
__global__ void k0_pack(const float* __restrict__ W, short* __restrict__ Wbf) {
  int idx = blockIdx.x * 256 + threadIdx.x;
  f32x4 v = *(const f32x4*)(W + (size_t)idx * 4);
  bf16x4 pk;
  pk[0] = f2bf(v[0]); pk[1] = f2bf(v[1]); pk[2] = f2bf(v[2]); pk[3] = f2bf(v[3]);
  *(bf16x4*)(Wbf + (size_t)idx * 4) = pk;
}

// ---------------- K0b: domain uniformity check ----------------
__global__ void k0_check(const float* __restrict__ domain, float* __restrict__ flag) {
  __shared__ int s_ok[4];
  const int t = threadIdx.x;
  float v0 = domain[0];
  bool ok = true;
  for (int x = t; x < 72 * 72; x += 256) ok = ok && (domain[x] == v0);
  unsigned long long m = __ballot(ok);
  if ((t & 63) == 0) s_ok[t >> 6] = (m == ~0ull) ? 1 : 0;
  __syncthreads();
  if (t == 0) {
    flag[0] = v0;
    flag[1] = (s_ok[0] && s_ok[1] && s_ok[2] && s_ok[3]) ? 1.f : 0.f;
  }
}

// ---------------- k2a: pre-scaled weights, wave-per-row (R9-proven) ----------------
__global__ __launch_bounds__(256) void k2a_weights(
    const float* __restrict__ dist, const float* __restrict__ bear,
    const float* __restrict__ head, const float* __restrict__ seqmask,
    const float* __restrict__ domain, const float* __restrict__ uflag,
    short* __restrict__ weBuf) {
  __shared__ float sMask[256];
  const int t = threadIdx.x;
  const int b = blockIdx.x >> 3;
  const int i0 = (blockIdx.x & 7) * 32;
  if (t < 256) sMask[t] = seqmask[b * 256 + t];
  __syncthreads();

  const int w = t >> 6, l = t & 63;
  const int j0 = l * 4;
  const float dval = uflag[0];
  const bool  uni  = uflag[1] != 0.f;
  const f32x4 mj = *(const f32x4*)(sMask + j0);

  f32x4 dv[8];
  #pragma unroll
  for (int rr = 0; rr < 8; ++rr) {
    int i = i0 + w * 8 + rr;
    dv[rr] = *(const f32x4*)(dist + ((size_t)b * 256 + i) * 256 + j0);
  }

  #pragma unroll
  for (int rr = 0; rr < 8; ++rr) {
    const int i = i0 + w * 8 + rr;
    const float mI = sMask[i];
    const size_t base = ((size_t)b * 256 + i) * 256;
    float ev[4];
    float rs = 0.f;
    if (uni) {
      #pragma unroll
      for (int e = 0; e < 4; ++e) {
        float wv = fmaxf(dval - dv[rr][e], 0.f);
        bool valid = (i != j0 + e) && (mI != 0.f) && (mj[e] != 0.f);
        float ex = (wv > 0.f) ? __expf(wv) : 0.f;
        ex = valid ? ex : 0.f;
        rs += ex;
        ev[e] = valid ? (ex + EPSC) : 0.f;
      }
    } else {
      f32x4 bv = *(const f32x4*)(bear + base + j0);
      f32x4 hv = *(const f32x4*)(head + base + j0);
      #pragma unroll
      for (int e = 0; e < 4; ++e) {
        float f1 = fminf(fmaxf(floorf((hv[e] + 2.5f) * 0.2f), 0.f), 71.f);
        float f2 = fminf(fmaxf(floorf((bv[e] + 2.5f) * 0.2f), 0.f), 71.f);
        float wv = fmaxf(domain[(int)(f1 * 72.f + f2)] - dv[rr][e], 0.f);
        bool valid = (i != j0 + e) && (mI != 0.f) && (mj[e] != 0.f);
        float ex = (wv > 0.f) ? __expf(wv) : 0.f;
        ex = valid ? ex : 0.f;
        rs += ex;
        ev[e] = valid ? (ex + EPSC) : 0.f;
      }
    }
    rs += __shfl_xor(rs, 1, 64);
    rs += __shfl_xor(rs, 2, 64);
    rs += __shfl_xor(rs, 4, 64);
    rs += __shfl_xor(rs, 8, 64);
    rs += __shfl_xor(rs, 16, 64);
    rs += __shfl_xor(rs, 32, 64);
    const float scale = 1.0f / (rs + 257.0f * EPSC);
    bf16x4 pk;
    pk[0] = f2bf(ev[0] * scale); pk[1] = f2bf(ev[1] * scale);
    pk[2] = f2bf(ev[2] * scale); pk[3] = f2bf(ev[3] * scale);
    *(bf16x4*)(weBuf + base + j0) = pk;
  }
}

// ---------------- k1_p1t: P1T = (H W1^T)^T, big barrier-free spans ----------------
// grid 512 (XCD-swizzled), block 512, LDS 65536 (two 32KB regions) -> 2 blocks/CU.
// 2 K-half rounds: stage 64KB -> bar -> 4 subs (no barriers). 3 barriers total.
__global__ __launch_bounds__(512, 4) void k1_p1t(
    const float* __restrict__ H, const short* __restrict__ Wbf,
    short* __restrict__ P1T) {
  extern __shared__ char sm[];
  const int t = threadIdx.x;
  const int x = blockIdx.x;
  const int blk = (x & 7) * 64 + (x >> 3);     // bijective: 512 = 8*64
  const int n0 = blk * 128;
  const int b  = n0 >> 8;
  const int jb = n0 & 255;

  const int wid = t >> 6, l = t & 63;
  const int lr = l & 15, lg = l >> 4;
  const int wr = wid & 3, wc = wid >> 2;
  const int r3 = l >> 3, sl = l & 7;
  const int sswz = (sl ^ r3) * 8;
  const int sw = (lr & 7) << 4;

  const size_t h0 = ((size_t)(n0 + wr * 32 + lr)) * 256;
  const size_t h1 = h0 + 16 * 256;

  f32x4 acc[2][8] = {};

  #pragma unroll
  for (int hhf = 0; hhf < 2; ++hhf) {          // K-half rounds
    if (hhf) __syncthreads();                  // prev compute done before overwrite
    // stage both 32KB regions of this K-half
    #pragma unroll
    for (int rg = 0; rg < 2; ++rg) {
      #pragma unroll
      for (int p = 0; p < 4; ++p) {
        int dd = wid * 8 + r3 + 64 * p;
        gload16(Wbf + (size_t)dd * 512 + hhf * 128 + rg * 64 + sswz,
                sm + rg * 32768 + (wid * 8 + 64 * p) * 128);
      }
    }
    __syncthreads();
    // 4 MFMA-subs, no barriers
    #pragma unroll
    for (int s4 = 0; s4 < 4; ++s4) {
      const int rg = s4 >> 1, sub = s4 & 1;
      const int kg = hhf * 128 + s4 * 32 + lg * 8;
      bf16x8 av0 = cvt8(H + h0 + kg);
      bf16x8 av1 = cvt8(H + h1 + kg);
      #pragma unroll
      for (int n = 0; n < 8; ++n) {
        const int d = wc * 128 + n * 16 + lr;
        bf16x8 bb = *(const bf16x8*)(sm + rg * 32768 + d * 128 + ((sub * 64 + lg * 16) ^ sw));
        acc[0][n] = __builtin_amdgcn_mfma_f32_16x16x32_bf16(av0, bb, acc[0][n], 0, 0, 0);
        acc[1][n] = __builtin_amdgcn_mfma_f32_16x16x32_bf16(av1, bb, acc[1][n], 0, 0, 0);
      }
    }
  }

  // epilogue: transposed write P1T[b][d][jb + wr*32 + m*16 + lg*4 + r]
  #pragma unroll
  for (int m = 0; m < 2; ++m) {
    #pragma unroll
    for (int n = 0; n < 8; ++n) {
      const int d = wc * 128 + n * 16 + lr;
      f32x4 v = acc[m][n];
      bf16x4 pk;
      pk[0] = f2bf(v[0]); pk[1] = f2bf(v[1]); pk[2] = f2bf(v[2]); pk[3] = f2bf(v[3]);
      *(bf16x4*)(P1T + (size_t)b * 65536 + (size_t)d * 256 + jb + wr * 32 + m * 16 + lg * 4) = pk;
    }
  }
}

// ---------------- k2b: out = weBuf @ P1T + bf16(H) @ W2 + bias, K=512 ----------------
// grid 512 (XCD-swizzled), block 512, LDS 66560 -> 2 blocks/CU.
// 4 K-quarter rounds: stage 64KB -> bar -> 4 subs (no barriers).
__global__ __launch_bounds__(512, 4) void k2b_gemm(
    const short* __restrict__ weBuf, const short* __restrict__ P1T,
    const short* __restrict__ Wbf, const float* __restrict__ H,
    const float* __restrict__ bias, float* __restrict__ out) {
  extern __shared__ char sm[];
  float* sBias = (float*)(sm + 65536);
  const int t = threadIdx.x;
  const int x = blockIdx.x;
  const int blk = (x & 7) * 64 + (x >> 3);     // bijective: 512 = 8*64
  const int b  = blk >> 1;
  const int i0 = (blk & 1) * 128;

  const int wid = t >> 6, l = t & 63;
  const int lr = l & 15, lg = l >> 4;
  const int wr = wid & 3, wc = wid >> 2;
  const int r3 = l >> 3, sl = l & 7;
  const int sswz = (sl ^ r3) * 8;
  const int sw = (lr & 7) << 4;

  const short* __restrict__ P1b = P1T + (size_t)b * 65536;
  const size_t a0 = ((size_t)b * 256 + i0 + wr * 32 + lr) * 256;
  const size_t a1 = a0 + 16 * 256;

  if (t < 256) sBias[t] = bias[t];

  f32x4 acc[2][8] = {};

  #pragma unroll
  for (int q = 0; q < 4; ++q) {                // K-quarter rounds (k = q*128)
    if (q) __syncthreads();
    #pragma unroll
    for (int rg = 0; rg < 2; ++rg) {
      #pragma unroll
      for (int p = 0; p < 4; ++p) {
        int dd = wid * 8 + r3 + 64 * p;
        if (q < 2)
          gload16(P1b + (size_t)dd * 256 + q * 128 + rg * 64 + sswz,
                  sm + rg * 32768 + (wid * 8 + 64 * p) * 128);
        else
          gload16(Wbf + (size_t)dd * 512 + 256 + (q - 2) * 128 + rg * 64 + sswz,
                  sm + rg * 32768 + (wid * 8 + 64 * p) * 128);
      }
    }
    __syncthreads();
    #pragma unroll
    for (int s4 = 0; s4 < 4; ++s4) {
      const int rg = s4 >> 1, sub = s4 & 1;
      const int ka = q * 128 + s4 * 32 + lg * 8;   // global concat-k 0..511
      bf16x8 av0, av1;
      if (ka < 256) {
        av0 = *(const bf16x8*)(weBuf + a0 + ka);
        av1 = *(const bf16x8*)(weBuf + a1 + ka);
      } else {
        av0 = cvt8(H + a0 + (ka - 256));
        av1 = cvt8(H + a1 + (ka - 256));
      }
      #pragma unroll
      for (int n = 0; n < 8; ++n) {
        const int d = wc * 128 + n * 16 + lr;
        bf16x8 bb = *(const bf16x8*)(sm + rg * 32768 + d * 128 + ((sub * 64 + lg * 16) ^ sw));
        acc[0][n] = __builtin_amdgcn_mfma_f32_16x16x32_bf16(av0, bb, acc[0][n], 0, 0, 0);
        acc[1][n] = __builtin_amdgcn_mfma_f32_16x16x32_bf16(av1, bb, acc[1][n], 0, 0, 0);
      }
    }
  }

  // epilogue: + bias, fp32 store
  #pragma unroll
  for (int m = 0; m < 2; ++m) {
    #pragma unroll
    for (int n = 0; n < 8; ++n) {
      const int d = wc * 128 + n * 16 + lr;
      const float bs = sBias[d];
      #pragma unroll
      for (int r = 0; r < 4; ++r) {
        const int row = i0 + wr * 32 + m * 16 + lg * 4 + r;
        out[((size_t)b * 256 + row) * 256 + d] = acc[m][n][r] + bs;
      }
    }
  }
}

extern "C" void kernel_launch(void* const* d_in, const int* in_sizes, int n_in,
                              void* d_out, int out_size, void* d_ws, size_t ws_size,
                              hipStream_t stream) {
  const float* hidden  = (const float*)d_in[0];
  const float* dist    = (const float*)d_in[1];
  const float* bear    = (const float*)d_in[2];
  const float* head    = (const float*)d_in[3];
  const float* seqmask = (const float*)d_in[4];
  const float* domain  = (const float*)d_in[5];
  const float* W       = (const float*)d_in[6];
  const float* bias    = (const float*)d_in[7];
  float* out = (float*)d_out;

  char* ws = (char*)d_ws;
  short* Wbf   = (short*)ws;                                 // 512 KB
  float* flag  = (float*)(ws + 524288);                      // 2 floats
  short* P1T   = (short*)(ws + (1u << 20));                  // 32 MB
  short* weBuf = (short*)(ws + (1u << 20) + (32u << 20));    // 32 MB

  k0_pack<<<128, 256, 0, stream>>>(W, Wbf);
  k0_check<<<1, 256, 0, stream>>>(domain, flag);
  k2a_weights<<<2048, 256, 0, stream>>>(dist, bear, head, seqmask, domain, flag, weBuf);
  k1_p1t<<<512, 512, 65536, stream>>>(hidden, Wbf, P1T);
  k2b_gemm<<<512, 512, 66560, stream>>>(weBuf, P1T, Wbf, hidden, bias, out);
}